// Round 3
// baseline (767.058 us; speedup 1.0000x reference)
//
#include <hip/hip_runtime.h>
#include <math.h>

// Problem constants
#define BB   16      // batch
#define IC   8       // in capsules
#define BI   128     // BB*IC
#define CIN  16      // conv in channels
#define WH   128     // input spatial
#define OWH  65      // output spatial (stride 2, pad 2, k 4)
#define NPIX (OWH*OWH)   // 4225
#define OC   8       // out capsules
#define COUT 16      // out channel per capsule
#define NOC  128     // OC*Cout
#define KTOT 256     // CIN*4*4
#define KC   64      // (fp32 fallback chunk)
#define NCHUNK 4

// MFMA kernel: K chunked by 32 (one mfma-K per chunk)
#define KCM  32
#define NCHM 8

typedef unsigned short ushortT;
typedef __bf16 bf16x8 __attribute__((ext_vector_type(8)));
typedef float  f32x4  __attribute__((ext_vector_type(4)));

union PackU { ushort4 h[2]; uint4 u; };

__device__ __forceinline__ ushortT f2bf(float f) {
    unsigned u = __float_as_uint(f);
    unsigned r = (u + 0x7fffu + ((u >> 16) & 1u)) >> 16;
    return (ushortT)r;
}

// ---------------------------------------------------------------------------
// Pre-pass 1: x fp32 -> bf16 (same layout)
// ---------------------------------------------------------------------------
__global__ void cvt_x_kernel(const float4* __restrict__ x,
                             ushort4* __restrict__ xbf, int n4)
{
    int stride = gridDim.x * blockDim.x;
    for (int i = blockIdx.x * blockDim.x + threadIdx.x; i < n4; i += stride) {
        float4 v = x[i];
        ushort4 o;
        o.x = f2bf(v.x); o.y = f2bf(v.y); o.z = f2bf(v.z); o.w = f2bf(v.w);
        xbf[i] = o;
    }
}

// ---------------------------------------------------------------------------
// Pre-pass 2: W fp32 [oc][k] -> bf16 prepacked fragment image:
//   Wbf[(kpg*128+oc)*8 + j]   (k = kpg*8 + j, kpg = 0..31)
// ---------------------------------------------------------------------------
__global__ void prep_w_kernel(const float* __restrict__ W,
                              ushortT* __restrict__ Wbf)
{
    int idx = blockIdx.x * 256 + threadIdx.x;   // 32768 total
    int oc = idx >> 8, k = idx & 255;
    int kpg = k >> 3, j = k & 7;
    Wbf[((size_t)kpg * 128 + oc) * 8 + j] = f2bf(W[idx]);
}

// ---------------------------------------------------------------------------
// Fused MFMA kernel: per-pixel 128x128x256 bf16 GEMM + fp32 routing in regs.
// 4 waves; wave w owns rows [64*(w>>1),+64) x cols [64*(w&1),+64)
// (4x4 tiles of 16x16). C/D: col=lane&15=c, row=4*quad+reg -> (b,i).
// KCM=32: one MFMA-K per chunk; small LDS (~20.6 KB) for 5+ blocks/CU.
// ---------------------------------------------------------------------------
__launch_bounds__(256, 5)
__global__ void capsconv_mfma(const ushortT* __restrict__ xbf,
                              const ushortT* __restrict__ Wbf,
                              const float* __restrict__ bias,
                              float* __restrict__ outbuf,
                              const int direct_out)
{
    __shared__ __align__(16) ushortT As[4 * 128 * 8];   // [kp][row][8] bf16, 8 KB
    __shared__ __align__(16) ushortT Bs[4 * 128 * 8];   // [kp][oc ][8] bf16, 8 KB
    __shared__ float cijs[64];       // [o][i]
    __shared__ float bijs[64];       // [o][i]
    __shared__ float aTmp[16 * 64];  // [b][o*8+i]

    const int t  = threadIdx.x;
    const int g8 = blockIdx.x;
    int p = (g8 & 7) * 529 + (g8 >> 3);     // XCD-contiguous pixel strips
    if (p >= NPIX) return;

    const int w  = t >> 6;       // wave id
    const int ln = t & 63;
    const int q  = ln >> 4;      // quad (k-group / acc row group)
    const int cL = ln & 15;      // lane col (c within tile)
    const int h  = q & 1;        // i-half
    const int mrow_base = 64 * (w >> 1);
    const int ncol_base = 64 * (w & 1);

    const int px = p / OWH;
    const int py = p % OWH;
    const int row0 = 2 * px - 2;
    const int col0 = 2 * py - 2;
    const bool interior = (px >= 1 && px <= 63 && py >= 1 && py <= 63);

    f32x4 acc[4][4];
#pragma unroll
    for (int mt = 0; mt < 4; ++mt)
#pragma unroll
        for (int nt = 0; nt < 4; ++nt) acc[mt][nt] = (f32x4){0.f, 0.f, 0.f, 0.f};

    ushort4 aR0[2], aR1[2];   // A staging: 2 k-packs (2 rows x 4 cols each)
    uint4   bR[2];            // B staging: 2 x 16B

    auto loadA = [&](int kc) {
#pragma unroll
        for (int g = 0; g < 2; ++g) {
            const int L  = g * 256 + t;          // 0..511
            const int bi = L & 127;
            const int pc = (L >> 7) & 3;         // 0..3
            const int ci = kc * 2 + (pc >> 1);
            const int r  = (pc & 1) * 2;
            const int ra = row0 + r;
            const int base = ((bi * CIN + ci) * WH + ra) * WH + col0;
            if (interior) {
                aR0[g] = *(const ushort4*)(xbf + base);
                aR1[g] = *(const ushort4*)(xbf + base + WH);
            } else {
                ushort4 v0, v1;
                ushortT* pv0 = (ushortT*)&v0;
                ushortT* pv1 = (ushortT*)&v1;
#pragma unroll
                for (int cc = 0; cc < 4; ++cc) {
                    const int col = col0 + cc;
                    const bool okc = (col >= 0 && col < WH);
                    const int ix0 = ((bi * CIN + ci) * WH + ra) * WH + col;
                    pv0[cc] = (okc && ra >= 0 && ra < WH) ? xbf[ix0] : (ushortT)0;
                    pv1[cc] = (okc && ra + 1 >= 0 && ra + 1 < WH) ? xbf[ix0 + WH] : (ushortT)0;
                }
                aR0[g] = v0; aR1[g] = v1;
            }
        }
    };
    auto loadB = [&](int kc) {
        const uint4* src = (const uint4*)Wbf + (size_t)kc * 512;
#pragma unroll
        for (int i = 0; i < 2; ++i) bR[i] = src[i * 256 + t];
    };

    loadA(0); loadB(0);

    for (int kc = 0; kc < NCHM; ++kc) {
        __syncthreads();   // prior chunk's LDS reads complete
#pragma unroll
        for (int g = 0; g < 2; ++g) {
            const int L  = g * 256 + t;
            const int bi = L & 127;
            const int pc = (L >> 7) & 3;
            PackU pk; pk.h[0] = aR0[g]; pk.h[1] = aR1[g];
            *(uint4*)&As[(pc * 128 + bi) * 8] = pk.u;
        }
#pragma unroll
        for (int i = 0; i < 2; ++i) ((uint4*)Bs)[i * 256 + t] = bR[i];
        __syncthreads();

        if (kc < NCHM - 1) { loadA(kc + 1); loadB(kc + 1); }

        {
            const int kb = q * 128;
            bf16x8 af[4], bf[4];
#pragma unroll
            for (int mt = 0; mt < 4; ++mt)
                af[mt] = *(const bf16x8*)&As[(kb + mrow_base + mt * 16 + cL) * 8];
#pragma unroll
            for (int nt = 0; nt < 4; ++nt)
                bf[nt] = *(const bf16x8*)&Bs[(kb + ncol_base + nt * 16 + cL) * 8];
#pragma unroll
            for (int mt = 0; mt < 4; ++mt)
#pragma unroll
                for (int nt = 0; nt < 4; ++nt)
                    acc[mt][nt] = __builtin_amdgcn_mfma_f32_16x16x32_bf16(
                        af[mt], bf[nt], acc[mt][nt], 0, 0, 0);
        }
    }

    // bias epilogue
#pragma unroll
    for (int nt = 0; nt < 4; ++nt) {
        const float bv = bias[ncol_base + nt * 16 + cL];
#pragma unroll
        for (int mt = 0; mt < 4; ++mt) acc[mt][nt] += bv;
    }

    // ---------------- dynamic routing (3 iters) ----------------
    // iter 0: b_ij = 0 -> c_ij = 1/8 exactly; no softmax, no barrier.
    for (int it = 0; it < 3; ++it) {
        float4 cf4[4];
        if (it == 0) {
#pragma unroll
            for (int nt = 0; nt < 4; ++nt)
                cf4[nt] = make_float4(0.125f, 0.125f, 0.125f, 0.125f);
        } else {
            __syncthreads();   // bijs update visible
            if (t < 8) {       // softmax over i for o = t
                const int oo = t;
                float mx = -1e30f;
#pragma unroll
                for (int i = 0; i < 8; ++i) mx = fmaxf(mx, bijs[oo * 8 + i]);
                float e[8]; float ssum = 0.f;
#pragma unroll
                for (int i = 0; i < 8; ++i) { e[i] = __expf(bijs[oo * 8 + i] - mx); ssum += e[i]; }
                const float inv = __builtin_amdgcn_rcpf(ssum);
#pragma unroll
                for (int i = 0; i < 8; ++i) cijs[oo * 8 + i] = e[i] * inv;
            }
            __syncthreads();
#pragma unroll
            for (int nt = 0; nt < 4; ++nt)
                cf4[nt] = *(const float4*)&cijs[(4 * (w & 1) + nt) * 8 + 4 * h];
        }

#pragma unroll
        for (int mt = 0; mt < 4; ++mt) {
            const int b = 8 * (w >> 1) + 2 * mt + (q >> 1);
#pragma unroll
            for (int nt = 0; nt < 4; ++nt) {
                const int o = 4 * (w & 1) + nt;
                const float4 cf = cf4[nt];
                float sp = cf.x * acc[mt][nt][0] + cf.y * acc[mt][nt][1]
                         + cf.z * acc[mt][nt][2] + cf.w * acc[mt][nt][3];
                float s = sp + __shfl_xor(sp, 16);
                float ssq = s * s;
#pragma unroll
                for (int d = 1; d < 16; d <<= 1) ssq += __shfl_xor(ssq, d);
                const float scale = sqrtf(ssq) * __builtin_amdgcn_rcpf(1.f + ssq);
                const float vj = s * scale;

                if (it == 2) {
                    if (q == 0 || q == 2) {
                        if (direct_out)
                            outbuf[(size_t)(b * NOC + o * 16 + cL) * NPIX + p] = vj;
                        else
                            outbuf[(size_t)p * 2048 + b * NOC + o * 16 + cL] = vj;
                    }
                } else {
                    f32x4 ap = acc[mt][nt] * vj;
#pragma unroll
                    for (int d = 1; d < 16; d <<= 1) {
                        ap[0] += __shfl_xor(ap[0], d);
                        ap[1] += __shfl_xor(ap[1], d);
                        ap[2] += __shfl_xor(ap[2], d);
                        ap[3] += __shfl_xor(ap[3], d);
                    }
                    if (cL == 0) {
                        float* dst = &aTmp[b * 64 + o * 8 + 4 * h];
                        dst[0] = ap[0]; dst[1] = ap[1]; dst[2] = ap[2]; dst[3] = ap[3];
                    }
                }
            }
        }
        if (it < 2) {
            __syncthreads();   // aTmp writes visible
            if (t < 64) {
                float s = 0.f;
#pragma unroll
                for (int b = 0; b < BB; ++b) s += aTmp[b * 64 + t];
                bijs[t] = (it == 0 ? 0.f : bijs[t]) + s * (1.f / 16.f);
            }
        }
    }
}

// ---------------------------------------------------------------------------
// [pixel][boc] -> [boc][pixel] tiled transpose
// ---------------------------------------------------------------------------
__global__ void transpose_kernel(const float* __restrict__ vtmp,
                                 float* __restrict__ out)
{
    __shared__ float tile[32][33];
    const int bp = blockIdx.x;
    const int bc = blockIdx.y;
    const int p0 = bp * 32, c0 = bc * 32;
    const int tx = threadIdx.x & 31, ty = threadIdx.x >> 5;

    for (int r = ty; r < 32; r += 8) {
        const int p = p0 + r;
        tile[r][tx] = (p < NPIX) ? vtmp[(size_t)p * 2048 + c0 + tx] : 0.f;
    }
    __syncthreads();
    for (int r = ty; r < 32; r += 8) {
        const int c = c0 + r;
        const int p = p0 + tx;
        if (p < NPIX) out[(size_t)c * NPIX + p] = tile[tx][r];
    }
}

// ---------------------------------------------------------------------------
// Round-1 fp32 fallback (proven correct) — used only if ws too small
// ---------------------------------------------------------------------------
__launch_bounds__(256, 2)
__global__ void capsconv_fp32(const float* __restrict__ x,
                              const float* __restrict__ Wc,
                              const float* __restrict__ bias,
                              float* __restrict__ outbuf,
                              const int direct_out)
{
    __shared__ float As[KC][BI];
    __shared__ float Bsh[KC][NOC];
    __shared__ float cij[64];
    __shared__ float bijs2[64];
    __shared__ float aTmp2[BB * 64];

    const int t  = threadIdx.x;
    const int tn = t & 15;
    const int tm = t >> 4;
    const int p  = blockIdx.x;
    const int px = p / OWH;
    const int py = p % OWH;
    const int row0 = 2 * px - 2;
    const int col0 = 2 * py - 2;
    const bool interior = (px >= 1 && px <= 63 && py >= 1 && py <= 63);

    float C[8][8];
#pragma unroll
    for (int r = 0; r < 8; ++r)
#pragma unroll
        for (int j = 0; j < 8; ++j) C[r][j] = 0.f;

    float areg[8][4];
    float breg[32];

    auto load_chunk = [&](int kc) {
#pragma unroll
        for (int g = 0; g < 8; ++g) {
            const int L    = g * 256 + t;
            const int bi   = L & 127;
            const int cikw = L >> 7;
            const int ci   = kc * 4 + (cikw >> 2);
            const int kw   = cikw & 3;
            const int row  = row0 + kw;
            const float* src = x + (((size_t)(bi * CIN + ci) * WH + row) * WH + col0);
            if (interior) {
                const float2 v01 = *(const float2*)(src);
                const float2 v23 = *(const float2*)(src + 2);
                areg[g][0] = v01.x; areg[g][1] = v01.y;
                areg[g][2] = v23.x; areg[g][3] = v23.y;
            } else {
#pragma unroll
                for (int kh = 0; kh < 4; ++kh) {
                    const int col = col0 + kh;
                    areg[g][kh] = (row >= 0 && row < WH && col >= 0 && col < WH)
                                      ? src[kh] : 0.f;
                }
            }
        }
        {
            const int oc  = t >> 1;
            const int kk0 = (t & 1) * 32;
            const float* wsrc = Wc + (size_t)oc * KTOT + kc * KC + kk0;
#pragma unroll
            for (int m = 0; m < 32; m += 4) {
                const float4 v = *(const float4*)(wsrc + m);
                breg[m] = v.x; breg[m+1] = v.y; breg[m+2] = v.z; breg[m+3] = v.w;
            }
        }
    };

    load_chunk(0);
    for (int kc = 0; kc < NCHUNK; ++kc) {
        __syncthreads();
#pragma unroll
        for (int g = 0; g < 8; ++g) {
            const int L    = g * 256 + t;
            const int bi   = L & 127;
            const int cikw = L >> 7;
            const int kkb  = cikw * 4;
#pragma unroll
            for (int kh = 0; kh < 4; ++kh) As[kkb + kh][bi] = areg[g][kh];
        }
        {
            const int oc  = t >> 1;
            const int kk0 = (t & 1) * 32;
#pragma unroll
            for (int m = 0; m < 32; ++m) Bsh[kk0 + m][oc] = breg[m];
        }
        __syncthreads();
        if (kc < NCHUNK - 1) load_chunk(kc + 1);
#pragma unroll 4
        for (int k = 0; k < KC; ++k) {
            float af[8], bf[8];
            *(float4*)(af)     = *(const float4*)&As[k][tm * 8];
            *(float4*)(af + 4) = *(const float4*)&As[k][tm * 8 + 4];
            *(float4*)(bf)     = *(const float4*)&Bsh[k][tn * 8];
            *(float4*)(bf + 4) = *(const float4*)&Bsh[k][tn * 8 + 4];
#pragma unroll
            for (int r = 0; r < 8; ++r)
#pragma unroll
                for (int j = 0; j < 8; ++j)
                    C[r][j] = fmaf(af[r], bf[j], C[r][j]);
        }
    }
#pragma unroll
    for (int j = 0; j < 8; ++j) {
        const float bj = bias[tn * 8 + j];
#pragma unroll
        for (int r = 0; r < 8; ++r) C[r][j] += bj;
    }

    const int o = tn >> 1;
    __syncthreads();
    if (t < 64) bijs2[t] = 0.f;

    float vout[8];
    for (int it = 0; it < 3; ++it) {
        __syncthreads();
        if (t < 8) {
            const int oo = t;
            float mx = -1e30f;
#pragma unroll
            for (int i = 0; i < 8; ++i) mx = fmaxf(mx, bijs2[i * 8 + oo]);
            float e[8]; float ssum = 0.f;
#pragma unroll
            for (int i = 0; i < 8; ++i) { e[i] = expf(bijs2[i * 8 + oo] - mx); ssum += e[i]; }
            const float inv = 1.f / ssum;
#pragma unroll
            for (int i = 0; i < 8; ++i) cij[i * 8 + oo] = e[i] * inv;
        }
        __syncthreads();
        float cf[8];
#pragma unroll
        for (int i = 0; i < 8; ++i) cf[i] = cij[i * 8 + o];
        float s[8];
#pragma unroll
        for (int j = 0; j < 8; ++j) {
            float acc = 0.f;
#pragma unroll
            for (int r = 0; r < 8; ++r) acc = fmaf(cf[r], C[r][j], acc);
            s[j] = acc;
        }
        float ssq = 0.f;
#pragma unroll
        for (int j = 0; j < 8; ++j) ssq = fmaf(s[j], s[j], ssq);
        ssq += __shfl_xor(ssq, 1);
        const float scale = ssq / ((1.f + ssq) * sqrtf(ssq));
        if (it == 2) {
#pragma unroll
            for (int j = 0; j < 8; ++j) vout[j] = s[j] * scale;
        } else {
            float ap[8];
#pragma unroll
            for (int r = 0; r < 8; ++r) {
                float acc = 0.f;
#pragma unroll
                for (int j = 0; j < 8; ++j) acc = fmaf(C[r][j], s[j] * scale, acc);
                ap[r] = acc;
            }
#pragma unroll
            for (int r = 0; r < 8; ++r) ap[r] += __shfl_xor(ap[r], 1);
            if ((tn & 1) == 0) {
#pragma unroll
                for (int r = 0; r < 8; ++r) aTmp2[tm * 64 + r * 8 + o] = ap[r];
            }
            __syncthreads();
            if (t < 64) {
                float acc = 0.f;
#pragma unroll
                for (int b = 0; b < BB; ++b) acc += aTmp2[b * 64 + t];
                bijs2[t] += acc * (1.f / 16.f);
            }
        }
    }
    if (direct_out) {
#pragma unroll
        for (int j = 0; j < 8; ++j)
            outbuf[(size_t)(tm * NOC + tn * 8 + j) * NPIX + p] = vout[j];
    } else {
        float4* dst = (float4*)(outbuf + (size_t)p * 2048 + tm * NOC + tn * 8);
        dst[0] = make_float4(vout[0], vout[1], vout[2], vout[3]);
        dst[1] = make_float4(vout[4], vout[5], vout[6], vout[7]);
    }
}

extern "C" void kernel_launch(void* const* d_in, const int* in_sizes, int n_in,
                              void* d_out, int out_size, void* d_ws, size_t ws_size,
                              hipStream_t stream)
{
    const float* x    = (const float*)d_in[0];
    const float* Wc   = (const float*)d_in[1];
    const float* bias = (const float*)d_in[2];
    float* out        = (float*)d_out;

    const size_t VT_BYTES = (size_t)NPIX * 2048 * sizeof(float);   // 34,611,200
    const size_t WB_OFF   = VT_BYTES;
    const size_t XB_OFF   = WB_OFF + 65536;
    const size_t TOTAL    = XB_OFF + (size_t)BI * CIN * WH * WH * 2;  // 101,785,600

    if (ws_size >= TOTAL) {
        float*   vtmp = (float*)d_ws;
        ushortT* Wbf  = (ushortT*)((char*)d_ws + WB_OFF);
        ushortT* xbf  = (ushortT*)((char*)d_ws + XB_OFF);

        cvt_x_kernel<<<8192, 256, 0, stream>>>((const float4*)x, (ushort4*)xbf,
                                               BI * CIN * WH * WH / 4);
        prep_w_kernel<<<128, 256, 0, stream>>>(Wc, Wbf);
        capsconv_mfma<<<529 * 8, 256, 0, stream>>>(xbf, Wbf, bias, vtmp, 0);
        dim3 g((NPIX + 31) / 32, 2048 / 32);
        transpose_kernel<<<g, 256, 0, stream>>>(vtmp, out);
    } else if (ws_size >= VT_BYTES) {
        float* vtmp = (float*)d_ws;
        capsconv_fp32<<<NPIX, 256, 0, stream>>>(x, Wc, bias, vtmp, 0);
        dim3 g((NPIX + 31) / 32, 2048 / 32);
        transpose_kernel<<<g, 256, 0, stream>>>(vtmp, out);
    } else {
        capsconv_fp32<<<NPIX, 256, 0, stream>>>(x, Wc, bias, out, 1);
    }
}

// Round 4
// 461.334 us; speedup vs baseline: 1.6627x; 1.6627x over previous
//
#include <hip/hip_runtime.h>
#include <math.h>

// Problem constants
#define BB   16      // batch
#define IC   8       // in capsules
#define BI   128     // BB*IC
#define CIN  16      // conv in channels
#define WH   128     // input spatial
#define OWH  65      // output spatial (stride 2, pad 2, k 4)
#define NPIX (OWH*OWH)   // 4225
#define OC   8       // out capsules
#define COUT 16      // out channel per capsule
#define NOC  128     // OC*Cout
#define KTOT 256     // CIN*4*4
#define KC   64      // (fp32 fallback chunk)
#define NCHUNK 4

// MFMA kernel: K chunked by 32 (one mfma-K per chunk), 8 chunks
#define NCHM 8

typedef unsigned short ushortT;
typedef __bf16 bf16x8 __attribute__((ext_vector_type(8)));
typedef float  f32x4  __attribute__((ext_vector_type(4)));

union PackU { ushort4 h[2]; uint4 u; };

__device__ __forceinline__ ushortT f2bf(float f) {
    unsigned u = __float_as_uint(f);
    unsigned r = (u + 0x7fffu + ((u >> 16) & 1u)) >> 16;
    return (ushortT)r;
}

// ---------------------------------------------------------------------------
// Pre-pass 1: x fp32 -> bf16 (same layout)
// ---------------------------------------------------------------------------
__global__ void cvt_x_kernel(const float4* __restrict__ x,
                             ushort4* __restrict__ xbf, int n4)
{
    int stride = gridDim.x * blockDim.x;
    for (int i = blockIdx.x * blockDim.x + threadIdx.x; i < n4; i += stride) {
        float4 v = x[i];
        ushort4 o;
        o.x = f2bf(v.x); o.y = f2bf(v.y); o.z = f2bf(v.z); o.w = f2bf(v.w);
        xbf[i] = o;
    }
}

// ---------------------------------------------------------------------------
// Pre-pass 2: W fp32 [oc][k] -> bf16 prepacked fragment image:
//   Wbf[(kpg*128+oc)*8 + j]   (k = kpg*8 + j, kpg = 0..31)
// ---------------------------------------------------------------------------
__global__ void prep_w_kernel(const float* __restrict__ W,
                              ushortT* __restrict__ Wbf)
{
    int idx = blockIdx.x * 256 + threadIdx.x;   // 32768 total
    int oc = idx >> 8, k = idx & 255;
    int kpg = k >> 3, j = k & 7;
    Wbf[((size_t)kpg * 128 + oc) * 8 + j] = f2bf(W[idx]);
}

// ---------------------------------------------------------------------------
// Fused MFMA kernel, 512 threads (8 waves). Wave w owns a 64x32 C quadrant:
// rows [64*(w>>2), +64) x cols [32*(w&3), +32) as 4x2 tiles of 16x16.
// acc = 32 regs/wave (half of R2/R3) -> no spill under __launch_bounds__(512,4).
// C/D: col=lane&15 -> oc-col c, row=4*quad+reg -> (b,i).
// ---------------------------------------------------------------------------
__launch_bounds__(512, 4)
__global__ void capsconv_mfma(const ushortT* __restrict__ xbf,
                              const ushortT* __restrict__ Wbf,
                              const float* __restrict__ bias,
                              float* __restrict__ outbuf,
                              const int direct_out)
{
    __shared__ __align__(16) ushortT As[4 * 128 * 8];   // [pc][row][8] bf16, 8 KB
    __shared__ __align__(16) ushortT Bs[4 * 128 * 8];   // [pc][oc ][8] bf16, 8 KB
    __shared__ float cijs[64];       // [o][i]
    __shared__ float bijs[64];       // [o][i]
    __shared__ float aTmp[16 * 64];  // [b][o*8+i]

    const int t  = threadIdx.x;      // 0..511
    const int g8 = blockIdx.x;
    int p = (g8 & 7) * 529 + (g8 >> 3);     // XCD-contiguous pixel strips
    if (p >= NPIX) return;

    const int w  = t >> 6;       // wave id 0..7
    const int ln = t & 63;
    const int q  = ln >> 4;      // quad
    const int cL = ln & 15;      // lane col (c within tile)
    const int h  = q & 1;        // i-half
    const int mrow_base = 64 * (w >> 2);   // 0 or 64
    const int ncol_base = 32 * (w & 3);    // 0,32,64,96

    const int px = p / OWH;
    const int py = p % OWH;
    const int row0 = 2 * px - 2;
    const int col0 = 2 * py - 2;
    const bool interior = (px >= 1 && px <= 63 && py >= 1 && py <= 63);

    f32x4 acc[4][2];
#pragma unroll
    for (int mt = 0; mt < 4; ++mt)
#pragma unroll
        for (int nt = 0; nt < 2; ++nt) acc[mt][nt] = (f32x4){0.f, 0.f, 0.f, 0.f};

    // A loader map: one 16B LDS row per thread per chunk
    const int bi = t & 127;
    const int pc = t >> 7;            // 0..3
    const int rr = (pc & 1) * 2;      // window row offset (0 or 2)

    ushort4 aR0, aR1;   // A staging: 2 rows x 4 cols
    uint4   bR;         // B staging: 16B

    auto loadA = [&](int kc) {
        const int ci = kc * 2 + (pc >> 1);
        const int ra = row0 + rr;
        const int base = ((bi * CIN + ci) * WH + ra) * WH + col0;
        if (interior) {
            aR0 = *(const ushort4*)(xbf + base);
            aR1 = *(const ushort4*)(xbf + base + WH);
        } else {
            ushort4 v0, v1;
            ushortT* pv0 = (ushortT*)&v0;
            ushortT* pv1 = (ushortT*)&v1;
#pragma unroll
            for (int cc = 0; cc < 4; ++cc) {
                const int col = col0 + cc;
                const bool okc = (col >= 0 && col < WH);
                const int ix0 = ((bi * CIN + ci) * WH + ra) * WH + col;
                pv0[cc] = (okc && ra >= 0 && ra < WH) ? xbf[ix0] : (ushortT)0;
                pv1[cc] = (okc && ra + 1 >= 0 && ra + 1 < WH) ? xbf[ix0 + WH] : (ushortT)0;
            }
            aR0 = v0; aR1 = v1;
        }
    };
    auto loadB = [&](int kc) {
        bR = ((const uint4*)Wbf)[kc * 512 + t];
    };

    loadA(0); loadB(0);

    for (int kc = 0; kc < NCHM; ++kc) {
        __syncthreads();   // prior chunk's frag reads complete
        {
            PackU pk; pk.h[0] = aR0; pk.h[1] = aR1;
            *(uint4*)&As[(pc * 128 + bi) * 8] = pk.u;
            ((uint4*)Bs)[t] = bR;
        }
        __syncthreads();

        if (kc < NCHM - 1) { loadA(kc + 1); loadB(kc + 1); }

        {
            const int kb = q * 128;
            bf16x8 af[4], bf[2];
#pragma unroll
            for (int mt = 0; mt < 4; ++mt)
                af[mt] = *(const bf16x8*)&As[(kb + mrow_base + mt * 16 + cL) * 8];
#pragma unroll
            for (int nt = 0; nt < 2; ++nt)
                bf[nt] = *(const bf16x8*)&Bs[(kb + ncol_base + nt * 16 + cL) * 8];
#pragma unroll
            for (int mt = 0; mt < 4; ++mt)
#pragma unroll
                for (int nt = 0; nt < 2; ++nt)
                    acc[mt][nt] = __builtin_amdgcn_mfma_f32_16x16x32_bf16(
                        af[mt], bf[nt], acc[mt][nt], 0, 0, 0);
        }
    }

    // bias epilogue
#pragma unroll
    for (int nt = 0; nt < 2; ++nt) {
        const float bv = bias[ncol_base + nt * 16 + cL];
#pragma unroll
        for (int mt = 0; mt < 4; ++mt) acc[mt][nt] += bv;
    }

    // ---------------- dynamic routing (3 iters) ----------------
    // iter 0: b_ij = 0 -> c_ij = 1/8 exactly; no softmax, no barrier.
    for (int it = 0; it < 3; ++it) {
        float4 cf4[2];
        if (it == 0) {
#pragma unroll
            for (int nt = 0; nt < 2; ++nt)
                cf4[nt] = make_float4(0.125f, 0.125f, 0.125f, 0.125f);
        } else {
            __syncthreads();   // bijs update visible
            if (t < 8) {       // softmax over i for o = t
                const int oo = t;
                float mx = -1e30f;
#pragma unroll
                for (int i = 0; i < 8; ++i) mx = fmaxf(mx, bijs[oo * 8 + i]);
                float e[8]; float ssum = 0.f;
#pragma unroll
                for (int i = 0; i < 8; ++i) { e[i] = __expf(bijs[oo * 8 + i] - mx); ssum += e[i]; }
                const float inv = __builtin_amdgcn_rcpf(ssum);
#pragma unroll
                for (int i = 0; i < 8; ++i) cijs[oo * 8 + i] = e[i] * inv;
            }
            __syncthreads();
#pragma unroll
            for (int nt = 0; nt < 2; ++nt)
                cf4[nt] = *(const float4*)&cijs[(2 * (w & 3) + nt) * 8 + 4 * h];
        }

#pragma unroll
        for (int mt = 0; mt < 4; ++mt) {
            const int b = 8 * (w >> 2) + 2 * mt + (q >> 1);
#pragma unroll
            for (int nt = 0; nt < 2; ++nt) {
                const int o = 2 * (w & 3) + nt;
                const float4 cf = cf4[nt];
                float sp = cf.x * acc[mt][nt][0] + cf.y * acc[mt][nt][1]
                         + cf.z * acc[mt][nt][2] + cf.w * acc[mt][nt][3];
                float s = sp + __shfl_xor(sp, 16);
                float ssq = s * s;
#pragma unroll
                for (int d = 1; d < 16; d <<= 1) ssq += __shfl_xor(ssq, d);
                const float scale = sqrtf(ssq) * __builtin_amdgcn_rcpf(1.f + ssq);
                const float vj = s * scale;

                if (it == 2) {
                    if (q == 0 || q == 2) {
                        if (direct_out)
                            outbuf[(size_t)(b * NOC + o * 16 + cL) * NPIX + p] = vj;
                        else
                            outbuf[(size_t)p * 2048 + b * NOC + o * 16 + cL] = vj;
                    }
                } else {
                    f32x4 ap = acc[mt][nt] * vj;
#pragma unroll
                    for (int d = 1; d < 16; d <<= 1) {
                        ap[0] += __shfl_xor(ap[0], d);
                        ap[1] += __shfl_xor(ap[1], d);
                        ap[2] += __shfl_xor(ap[2], d);
                        ap[3] += __shfl_xor(ap[3], d);
                    }
                    if (cL == 0) {
                        float* dst = &aTmp[b * 64 + o * 8 + 4 * h];
                        dst[0] = ap[0]; dst[1] = ap[1]; dst[2] = ap[2]; dst[3] = ap[3];
                    }
                }
            }
        }
        if (it < 2) {
            __syncthreads();   // aTmp writes visible
            if (t < 64) {
                float s = 0.f;
#pragma unroll
                for (int b = 0; b < BB; ++b) s += aTmp[b * 64 + t];
                bijs[t] = (it == 0 ? 0.f : bijs[t]) + s * (1.f / 16.f);
            }
        }
    }
}

// ---------------------------------------------------------------------------
// [pixel][boc] -> [boc][pixel] tiled transpose
// ---------------------------------------------------------------------------
__global__ void transpose_kernel(const float* __restrict__ vtmp,
                                 float* __restrict__ out)
{
    __shared__ float tile[32][33];
    const int bp = blockIdx.x;
    const int bc = blockIdx.y;
    const int p0 = bp * 32, c0 = bc * 32;
    const int tx = threadIdx.x & 31, ty = threadIdx.x >> 5;

    for (int r = ty; r < 32; r += 8) {
        const int p = p0 + r;
        tile[r][tx] = (p < NPIX) ? vtmp[(size_t)p * 2048 + c0 + tx] : 0.f;
    }
    __syncthreads();
    for (int r = ty; r < 32; r += 8) {
        const int c = c0 + r;
        const int p = p0 + tx;
        if (p < NPIX) out[(size_t)c * NPIX + p] = tile[tx][r];
    }
}

// ---------------------------------------------------------------------------
// Round-1 fp32 fallback (proven correct) — used only if ws too small
// ---------------------------------------------------------------------------
__launch_bounds__(256, 2)
__global__ void capsconv_fp32(const float* __restrict__ x,
                              const float* __restrict__ Wc,
                              const float* __restrict__ bias,
                              float* __restrict__ outbuf,
                              const int direct_out)
{
    __shared__ float As[KC][BI];
    __shared__ float Bsh[KC][NOC];
    __shared__ float cij[64];
    __shared__ float bijs2[64];
    __shared__ float aTmp2[BB * 64];

    const int t  = threadIdx.x;
    const int tn = t & 15;
    const int tm = t >> 4;
    const int p  = blockIdx.x;
    const int px = p / OWH;
    const int py = p % OWH;
    const int row0 = 2 * px - 2;
    const int col0 = 2 * py - 2;
    const bool interior = (px >= 1 && px <= 63 && py >= 1 && py <= 63);

    float C[8][8];
#pragma unroll
    for (int r = 0; r < 8; ++r)
#pragma unroll
        for (int j = 0; j < 8; ++j) C[r][j] = 0.f;

    float areg[8][4];
    float breg[32];

    auto load_chunk = [&](int kc) {
#pragma unroll
        for (int g = 0; g < 8; ++g) {
            const int L    = g * 256 + t;
            const int bi   = L & 127;
            const int cikw = L >> 7;
            const int ci   = kc * 4 + (cikw >> 2);
            const int kw   = cikw & 3;
            const int row  = row0 + kw;
            const float* src = x + (((size_t)(bi * CIN + ci) * WH + row) * WH + col0);
            if (interior) {
                const float2 v01 = *(const float2*)(src);
                const float2 v23 = *(const float2*)(src + 2);
                areg[g][0] = v01.x; areg[g][1] = v01.y;
                areg[g][2] = v23.x; areg[g][3] = v23.y;
            } else {
#pragma unroll
                for (int kh = 0; kh < 4; ++kh) {
                    const int col = col0 + kh;
                    areg[g][kh] = (row >= 0 && row < WH && col >= 0 && col < WH)
                                      ? src[kh] : 0.f;
                }
            }
        }
        {
            const int oc  = t >> 1;
            const int kk0 = (t & 1) * 32;
            const float* wsrc = Wc + (size_t)oc * KTOT + kc * KC + kk0;
#pragma unroll
            for (int m = 0; m < 32; m += 4) {
                const float4 v = *(const float4*)(wsrc + m);
                breg[m] = v.x; breg[m+1] = v.y; breg[m+2] = v.z; breg[m+3] = v.w;
            }
        }
    };

    load_chunk(0);
    for (int kc = 0; kc < NCHUNK; ++kc) {
        __syncthreads();
#pragma unroll
        for (int g = 0; g < 8; ++g) {
            const int L    = g * 256 + t;
            const int bi   = L & 127;
            const int cikw = L >> 7;
            const int kkb  = cikw * 4;
#pragma unroll
            for (int kh = 0; kh < 4; ++kh) As[kkb + kh][bi] = areg[g][kh];
        }
        {
            const int oc  = t >> 1;
            const int kk0 = (t & 1) * 32;
#pragma unroll
            for (int m = 0; m < 32; ++m) Bsh[kk0 + m][oc] = breg[m];
        }
        __syncthreads();
        if (kc < NCHUNK - 1) load_chunk(kc + 1);
#pragma unroll 4
        for (int k = 0; k < KC; ++k) {
            float af[8], bf[8];
            *(float4*)(af)     = *(const float4*)&As[k][tm * 8];
            *(float4*)(af + 4) = *(const float4*)&As[k][tm * 8 + 4];
            *(float4*)(bf)     = *(const float4*)&Bsh[k][tn * 8];
            *(float4*)(bf + 4) = *(const float4*)&Bsh[k][tn * 8 + 4];
#pragma unroll
            for (int r = 0; r < 8; ++r)
#pragma unroll
                for (int j = 0; j < 8; ++j)
                    C[r][j] = fmaf(af[r], bf[j], C[r][j]);
        }
    }
#pragma unroll
    for (int j = 0; j < 8; ++j) {
        const float bj = bias[tn * 8 + j];
#pragma unroll
        for (int r = 0; r < 8; ++r) C[r][j] += bj;
    }

    const int o = tn >> 1;
    __syncthreads();
    if (t < 64) bijs2[t] = 0.f;

    float vout[8];
    for (int it = 0; it < 3; ++it) {
        __syncthreads();
        if (t < 8) {
            const int oo = t;
            float mx = -1e30f;
#pragma unroll
            for (int i = 0; i < 8; ++i) mx = fmaxf(mx, bijs2[i * 8 + oo]);
            float e[8]; float ssum = 0.f;
#pragma unroll
            for (int i = 0; i < 8; ++i) { e[i] = expf(bijs2[i * 8 + oo] - mx); ssum += e[i]; }
            const float inv = 1.f / ssum;
#pragma unroll
            for (int i = 0; i < 8; ++i) cij[i * 8 + oo] = e[i] * inv;
        }
        __syncthreads();
        float cf[8];
#pragma unroll
        for (int i = 0; i < 8; ++i) cf[i] = cij[i * 8 + o];
        float s[8];
#pragma unroll
        for (int j = 0; j < 8; ++j) {
            float acc = 0.f;
#pragma unroll
            for (int r = 0; r < 8; ++r) acc = fmaf(cf[r], C[r][j], acc);
            s[j] = acc;
        }
        float ssq = 0.f;
#pragma unroll
        for (int j = 0; j < 8; ++j) ssq = fmaf(s[j], s[j], ssq);
        ssq += __shfl_xor(ssq, 1);
        const float scale = ssq / ((1.f + ssq) * sqrtf(ssq));
        if (it == 2) {
#pragma unroll
            for (int j = 0; j < 8; ++j) vout[j] = s[j] * scale;
        } else {
            float ap[8];
#pragma unroll
            for (int r = 0; r < 8; ++r) {
                float acc = 0.f;
#pragma unroll
                for (int j = 0; j < 8; ++j) acc = fmaf(C[r][j], s[j] * scale, acc);
                ap[r] = acc;
            }
#pragma unroll
            for (int r = 0; r < 8; ++r) ap[r] += __shfl_xor(ap[r], 1);
            if ((tn & 1) == 0) {
#pragma unroll
                for (int r = 0; r < 8; ++r) aTmp2[tm * 64 + r * 8 + o] = ap[r];
            }
            __syncthreads();
            if (t < 64) {
                float acc = 0.f;
#pragma unroll
                for (int b = 0; b < BB; ++b) acc += aTmp2[b * 64 + t];
                bijs2[t] += acc * (1.f / 16.f);
            }
        }
    }
    if (direct_out) {
#pragma unroll
        for (int j = 0; j < 8; ++j)
            outbuf[(size_t)(tm * NOC + tn * 8 + j) * NPIX + p] = vout[j];
    } else {
        float4* dst = (float4*)(outbuf + (size_t)p * 2048 + tm * NOC + tn * 8);
        dst[0] = make_float4(vout[0], vout[1], vout[2], vout[3]);
        dst[1] = make_float4(vout[4], vout[5], vout[6], vout[7]);
    }
}

extern "C" void kernel_launch(void* const* d_in, const int* in_sizes, int n_in,
                              void* d_out, int out_size, void* d_ws, size_t ws_size,
                              hipStream_t stream)
{
    const float* x    = (const float*)d_in[0];
    const float* Wc   = (const float*)d_in[1];
    const float* bias = (const float*)d_in[2];
    float* out        = (float*)d_out;

    const size_t VT_BYTES = (size_t)NPIX * 2048 * sizeof(float);   // 34,611,200
    const size_t WB_OFF   = VT_BYTES;
    const size_t XB_OFF   = WB_OFF + 65536;
    const size_t TOTAL    = XB_OFF + (size_t)BI * CIN * WH * WH * 2;  // 101,785,600

    if (ws_size >= TOTAL) {
        float*   vtmp = (float*)d_ws;
        ushortT* Wbf  = (ushortT*)((char*)d_ws + WB_OFF);
        ushortT* xbf  = (ushortT*)((char*)d_ws + XB_OFF);

        cvt_x_kernel<<<8192, 256, 0, stream>>>((const float4*)x, (ushort4*)xbf,
                                               BI * CIN * WH * WH / 4);
        prep_w_kernel<<<128, 256, 0, stream>>>(Wc, Wbf);
        capsconv_mfma<<<529 * 8, 512, 0, stream>>>(xbf, Wbf, bias, vtmp, 0);
        dim3 g((NPIX + 31) / 32, 2048 / 32);
        transpose_kernel<<<g, 256, 0, stream>>>(vtmp, out);
    } else if (ws_size >= VT_BYTES) {
        float* vtmp = (float*)d_ws;
        capsconv_fp32<<<NPIX, 256, 0, stream>>>(x, Wc, bias, vtmp, 0);
        dim3 g((NPIX + 31) / 32, 2048 / 32);
        transpose_kernel<<<g, 256, 0, stream>>>(vtmp, out);
    } else {
        capsconv_fp32<<<NPIX, 256, 0, stream>>>(x, Wc, bias, out, 1);
    }
}

// Round 5
// 459.312 us; speedup vs baseline: 1.6700x; 1.0044x over previous
//
#include <hip/hip_runtime.h>
#include <math.h>

// Problem constants
#define BB   16      // batch
#define IC   8       // in capsules
#define BI   128     // BB*IC
#define CIN  16      // conv in channels
#define WH   128     // input spatial
#define OWH  65      // output spatial (stride 2, pad 2, k 4)
#define NPIX (OWH*OWH)   // 4225
#define OC   8       // out capsules
#define COUT 16      // out channel per capsule
#define NOC  128     // OC*Cout
#define KTOT 256     // CIN*4*4
#define KC   64      // (fp32 fallback chunk)
#define NCHUNK 4

// MFMA kernel: K chunked by 32 (one mfma-K per chunk), 8 chunks
#define NCHM 8

typedef unsigned short ushortT;
typedef __bf16 bf16x8 __attribute__((ext_vector_type(8)));
typedef float  f32x4  __attribute__((ext_vector_type(4)));

union PackU { ushort4 h[2]; uint4 u; };

__device__ __forceinline__ ushortT f2bf(float f) {
    unsigned u = __float_as_uint(f);
    unsigned r = (u + 0x7fffu + ((u >> 16) & 1u)) >> 16;
    return (ushortT)r;
}

// ---------------------------------------------------------------------------
// Pre-pass 1: x fp32 -> bf16 (same layout)
// ---------------------------------------------------------------------------
__global__ void cvt_x_kernel(const float4* __restrict__ x,
                             ushort4* __restrict__ xbf, int n4)
{
    int stride = gridDim.x * blockDim.x;
    for (int i = blockIdx.x * blockDim.x + threadIdx.x; i < n4; i += stride) {
        float4 v = x[i];
        ushort4 o;
        o.x = f2bf(v.x); o.y = f2bf(v.y); o.z = f2bf(v.z); o.w = f2bf(v.w);
        xbf[i] = o;
    }
}

// ---------------------------------------------------------------------------
// Pre-pass 2: W fp32 [oc][k] -> bf16 prepacked fragment image:
//   Wbf[(kpg*128+oc)*8 + j]   (k = kpg*8 + j, kpg = 0..31)
// ---------------------------------------------------------------------------
__global__ void prep_w_kernel(const float* __restrict__ W,
                              ushortT* __restrict__ Wbf)
{
    int idx = blockIdx.x * 256 + threadIdx.x;   // 32768 total
    int oc = idx >> 8, k = idx & 255;
    int kpg = k >> 3, j = k & 7;
    Wbf[((size_t)kpg * 128 + oc) * 8 + j] = f2bf(W[idx]);
}

// ---------------------------------------------------------------------------
// Fused MFMA kernel, 512 threads (8 waves). Wave w owns a 64x32 C quadrant:
// rows [64*(w>>2), +64) x cols [32*(w&3), +32) as 4x2 tiles of 16x16.
// Double-buffered LDS: ONE barrier per K-chunk; next chunk's global loads
// issue right after the barrier so their vmcnt-wait lands after the MFMAs.
// Routing boundaries: fused wave-0 reduce+softmax (2 barriers, not 3).
// C/D: col=lane&15 -> oc-col c, row=4*quad+reg -> (b,i).
// ---------------------------------------------------------------------------
__launch_bounds__(512, 4)
__global__ void capsconv_mfma(const ushortT* __restrict__ xbf,
                              const ushortT* __restrict__ Wbf,
                              const float* __restrict__ bias,
                              float* __restrict__ outbuf,
                              const int direct_out)
{
    __shared__ __align__(16) ushortT As[2][4 * 128 * 8];   // 2 x 8 KB
    __shared__ __align__(16) ushortT Bs[2][4 * 128 * 8];   // 2 x 8 KB
    __shared__ float cijs[64];       // [o][i]
    __shared__ float bijs[64];       // [o][i] (written/read by wave 0 only)
    __shared__ float aTmp[16 * 64];  // [b][o*8+i]

    const int t  = threadIdx.x;      // 0..511
    const int g8 = blockIdx.x;
    int p = (g8 & 7) * 529 + (g8 >> 3);     // XCD-contiguous pixel strips
    if (p >= NPIX) return;

    const int w  = t >> 6;       // wave id 0..7
    const int ln = t & 63;
    const int q  = ln >> 4;      // quad
    const int cL = ln & 15;      // lane col (c within tile)
    const int h  = q & 1;        // i-half
    const int mrow_base = 64 * (w >> 2);   // 0 or 64
    const int ncol_base = 32 * (w & 3);    // 0,32,64,96

    const int px = p / OWH;
    const int py = p % OWH;
    const int row0 = 2 * px - 2;
    const int col0 = 2 * py - 2;
    const bool interior = (px >= 1 && px <= 63 && py >= 1 && py <= 63);

    f32x4 acc[4][2];
#pragma unroll
    for (int mt = 0; mt < 4; ++mt)
#pragma unroll
        for (int nt = 0; nt < 2; ++nt) acc[mt][nt] = (f32x4){0.f, 0.f, 0.f, 0.f};

    // A loader map: one 16B LDS row per thread per chunk
    const int bi = t & 127;
    const int pc = t >> 7;            // 0..3
    const int rr = (pc & 1) * 2;      // window row offset (0 or 2)

    ushort4 aR0, aR1;   // A staging: 2 rows x 4 cols
    uint4   bR;         // B staging: 16B

    auto loadA = [&](int kc) {
        const int ci = kc * 2 + (pc >> 1);
        const int ra = row0 + rr;
        const int base = ((bi * CIN + ci) * WH + ra) * WH + col0;
        if (interior) {
            aR0 = *(const ushort4*)(xbf + base);
            aR1 = *(const ushort4*)(xbf + base + WH);
        } else {
            ushort4 v0, v1;
            ushortT* pv0 = (ushortT*)&v0;
            ushortT* pv1 = (ushortT*)&v1;
#pragma unroll
            for (int cc = 0; cc < 4; ++cc) {
                const int col = col0 + cc;
                const bool okc = (col >= 0 && col < WH);
                const int ix0 = ((bi * CIN + ci) * WH + ra) * WH + col;
                pv0[cc] = (okc && ra >= 0 && ra < WH) ? xbf[ix0] : (ushortT)0;
                pv1[cc] = (okc && ra + 1 >= 0 && ra + 1 < WH) ? xbf[ix0 + WH] : (ushortT)0;
            }
            aR0 = v0; aR1 = v1;
        }
    };
    auto loadB = [&](int kc) {
        bR = ((const uint4*)Wbf)[kc * 512 + t];
    };
    auto storeAB = [&](int buf) {
        PackU pk; pk.h[0] = aR0; pk.h[1] = aR1;
        *(uint4*)&As[buf][(pc * 128 + bi) * 8] = pk.u;
        ((uint4*)Bs[buf])[t] = bR;
    };

    loadA(0); loadB(0);
    storeAB(0);

    for (int kc = 0; kc < NCHM; ++kc) {
        __syncthreads();   // buf[kc&1] writes visible; old reads of buf[(kc+1)&1] done
        if (kc < NCHM - 1) { loadA(kc + 1); loadB(kc + 1); }   // latency overlapped

        {
            const int buf = kc & 1;
            const int kb = q * 128;
            bf16x8 af[4], bf[2];
#pragma unroll
            for (int mt = 0; mt < 4; ++mt)
                af[mt] = *(const bf16x8*)&As[buf][(kb + mrow_base + mt * 16 + cL) * 8];
#pragma unroll
            for (int nt = 0; nt < 2; ++nt)
                bf[nt] = *(const bf16x8*)&Bs[buf][(kb + ncol_base + nt * 16 + cL) * 8];
#pragma unroll
            for (int mt = 0; mt < 4; ++mt)
#pragma unroll
                for (int nt = 0; nt < 2; ++nt)
                    acc[mt][nt] = __builtin_amdgcn_mfma_f32_16x16x32_bf16(
                        af[mt], bf[nt], acc[mt][nt], 0, 0, 0);
        }

        if (kc < NCHM - 1) storeAB((kc + 1) & 1);   // vmcnt wait lands here
    }

    // bias epilogue
#pragma unroll
    for (int nt = 0; nt < 2; ++nt) {
        const float bv = bias[ncol_base + nt * 16 + cL];
#pragma unroll
        for (int mt = 0; mt < 4; ++mt) acc[mt][nt] += bv;
    }

    // ---------------- dynamic routing (3 iters) ----------------
    // iter 0: b_ij = 0 -> c_ij = 1/8 exactly (no softmax needed).
    for (int it = 0; it < 3; ++it) {
        float4 cf4[2];
        if (it == 0) {
#pragma unroll
            for (int nt = 0; nt < 2; ++nt)
                cf4[nt] = make_float4(0.125f, 0.125f, 0.125f, 0.125f);
        } else {
            // cijs already visible (barrier at end of previous boundary)
#pragma unroll
            for (int nt = 0; nt < 2; ++nt)
                cf4[nt] = *(const float4*)&cijs[(2 * (w & 3) + nt) * 8 + 4 * h];
        }

#pragma unroll
        for (int mt = 0; mt < 4; ++mt) {
            const int b = 8 * (w >> 2) + 2 * mt + (q >> 1);
#pragma unroll
            for (int nt = 0; nt < 2; ++nt) {
                const int o = 2 * (w & 3) + nt;
                const float4 cf = cf4[nt];
                float sp = cf.x * acc[mt][nt][0] + cf.y * acc[mt][nt][1]
                         + cf.z * acc[mt][nt][2] + cf.w * acc[mt][nt][3];
                float s = sp + __shfl_xor(sp, 16);
                float ssq = s * s;
#pragma unroll
                for (int d = 1; d < 16; d <<= 1) ssq += __shfl_xor(ssq, d);
                const float scale = sqrtf(ssq) * __builtin_amdgcn_rcpf(1.f + ssq);
                const float vj = s * scale;

                if (it == 2) {
                    if (q == 0 || q == 2) {
                        if (direct_out)
                            outbuf[(size_t)(b * NOC + o * 16 + cL) * NPIX + p] = vj;
                        else
                            outbuf[(size_t)p * 2048 + b * NOC + o * 16 + cL] = vj;
                    }
                } else {
                    f32x4 ap = acc[mt][nt] * vj;
#pragma unroll
                    for (int d = 1; d < 16; d <<= 1) {
                        ap[0] += __shfl_xor(ap[0], d);
                        ap[1] += __shfl_xor(ap[1], d);
                        ap[2] += __shfl_xor(ap[2], d);
                        ap[3] += __shfl_xor(ap[3], d);
                    }
                    if (cL == 0) {
                        float* dst = &aTmp[b * 64 + o * 8 + 4 * h];
                        dst[0] = ap[0]; dst[1] = ap[1]; dst[2] = ap[2]; dst[3] = ap[3];
                    }
                }
            }
        }
        if (it < 2) {
            __syncthreads();   // aTmp writes visible
            if (t < 64) {
                // fused: bij update + softmax, all in wave 0 (lane = o*8+i)
                float sum = 0.f;
#pragma unroll
                for (int b = 0; b < BB; ++b) sum += aTmp[b * 64 + t];
                float bij = (it == 0 ? 0.f : bijs[t]) + sum * (1.f / 16.f);
                bijs[t] = bij;   // wave-0 local across iterations
                float mx = bij;
                mx = fmaxf(mx, __shfl_xor(mx, 1));
                mx = fmaxf(mx, __shfl_xor(mx, 2));
                mx = fmaxf(mx, __shfl_xor(mx, 4));
                float e = __expf(bij - mx);
                float se = e;
                se += __shfl_xor(se, 1);
                se += __shfl_xor(se, 2);
                se += __shfl_xor(se, 4);
                cijs[t] = e * __builtin_amdgcn_rcpf(se);
            }
            __syncthreads();   // cijs (and aTmp reads) done
        }
    }
}

// ---------------------------------------------------------------------------
// [pixel][boc] -> [boc][pixel] tiled transpose
// ---------------------------------------------------------------------------
__global__ void transpose_kernel(const float* __restrict__ vtmp,
                                 float* __restrict__ out)
{
    __shared__ float tile[32][33];
    const int bp = blockIdx.x;
    const int bc = blockIdx.y;
    const int p0 = bp * 32, c0 = bc * 32;
    const int tx = threadIdx.x & 31, ty = threadIdx.x >> 5;

    for (int r = ty; r < 32; r += 8) {
        const int p = p0 + r;
        tile[r][tx] = (p < NPIX) ? vtmp[(size_t)p * 2048 + c0 + tx] : 0.f;
    }
    __syncthreads();
    for (int r = ty; r < 32; r += 8) {
        const int c = c0 + r;
        const int p = p0 + tx;
        if (p < NPIX) out[(size_t)c * NPIX + p] = tile[tx][r];
    }
}

// ---------------------------------------------------------------------------
// Round-1 fp32 fallback (proven correct) — used only if ws too small
// ---------------------------------------------------------------------------
__launch_bounds__(256, 2)
__global__ void capsconv_fp32(const float* __restrict__ x,
                              const float* __restrict__ Wc,
                              const float* __restrict__ bias,
                              float* __restrict__ outbuf,
                              const int direct_out)
{
    __shared__ float As[KC][BI];
    __shared__ float Bsh[KC][NOC];
    __shared__ float cij[64];
    __shared__ float bijs2[64];
    __shared__ float aTmp2[BB * 64];

    const int t  = threadIdx.x;
    const int tn = t & 15;
    const int tm = t >> 4;
    const int p  = blockIdx.x;
    const int px = p / OWH;
    const int py = p % OWH;
    const int row0 = 2 * px - 2;
    const int col0 = 2 * py - 2;
    const bool interior = (px >= 1 && px <= 63 && py >= 1 && py <= 63);

    float C[8][8];
#pragma unroll
    for (int r = 0; r < 8; ++r)
#pragma unroll
        for (int j = 0; j < 8; ++j) C[r][j] = 0.f;

    float areg[8][4];
    float breg[32];

    auto load_chunk = [&](int kc) {
#pragma unroll
        for (int g = 0; g < 8; ++g) {
            const int L    = g * 256 + t;
            const int bi   = L & 127;
            const int cikw = L >> 7;
            const int ci   = kc * 4 + (cikw >> 2);
            const int kw   = cikw & 3;
            const int row  = row0 + kw;
            const float* src = x + (((size_t)(bi * CIN + ci) * WH + row) * WH + col0);
            if (interior) {
                const float2 v01 = *(const float2*)(src);
                const float2 v23 = *(const float2*)(src + 2);
                areg[g][0] = v01.x; areg[g][1] = v01.y;
                areg[g][2] = v23.x; areg[g][3] = v23.y;
            } else {
#pragma unroll
                for (int kh = 0; kh < 4; ++kh) {
                    const int col = col0 + kh;
                    areg[g][kh] = (row >= 0 && row < WH && col >= 0 && col < WH)
                                      ? src[kh] : 0.f;
                }
            }
        }
        {
            const int oc  = t >> 1;
            const int kk0 = (t & 1) * 32;
            const float* wsrc = Wc + (size_t)oc * KTOT + kc * KC + kk0;
#pragma unroll
            for (int m = 0; m < 32; m += 4) {
                const float4 v = *(const float4*)(wsrc + m);
                breg[m] = v.x; breg[m+1] = v.y; breg[m+2] = v.z; breg[m+3] = v.w;
            }
        }
    };

    load_chunk(0);
    for (int kc = 0; kc < NCHUNK; ++kc) {
        __syncthreads();
#pragma unroll
        for (int g = 0; g < 8; ++g) {
            const int L    = g * 256 + t;
            const int bi   = L & 127;
            const int cikw = L >> 7;
            const int kkb  = cikw * 4;
#pragma unroll
            for (int kh = 0; kh < 4; ++kh) As[kkb + kh][bi] = areg[g][kh];
        }
        {
            const int oc  = t >> 1;
            const int kk0 = (t & 1) * 32;
#pragma unroll
            for (int m = 0; m < 32; ++m) Bsh[kk0 + m][oc] = breg[m];
        }
        __syncthreads();
        if (kc < NCHUNK - 1) load_chunk(kc + 1);
#pragma unroll 4
        for (int k = 0; k < KC; ++k) {
            float af[8], bf[8];
            *(float4*)(af)     = *(const float4*)&As[k][tm * 8];
            *(float4*)(af + 4) = *(const float4*)&As[k][tm * 8 + 4];
            *(float4*)(bf)     = *(const float4*)&Bsh[k][tn * 8];
            *(float4*)(bf + 4) = *(const float4*)&Bsh[k][tn * 8 + 4];
#pragma unroll
            for (int r = 0; r < 8; ++r)
#pragma unroll
                for (int j = 0; j < 8; ++j)
                    C[r][j] = fmaf(af[r], bf[j], C[r][j]);
        }
    }
#pragma unroll
    for (int j = 0; j < 8; ++j) {
        const float bj = bias[tn * 8 + j];
#pragma unroll
        for (int r = 0; r < 8; ++r) C[r][j] += bj;
    }

    const int o = tn >> 1;
    __syncthreads();
    if (t < 64) bijs2[t] = 0.f;

    float vout[8];
    for (int it = 0; it < 3; ++it) {
        __syncthreads();
        if (t < 8) {
            const int oo = t;
            float mx = -1e30f;
#pragma unroll
            for (int i = 0; i < 8; ++i) mx = fmaxf(mx, bijs2[i * 8 + oo]);
            float e[8]; float ssum = 0.f;
#pragma unroll
            for (int i = 0; i < 8; ++i) { e[i] = expf(bijs2[i * 8 + oo] - mx); ssum += e[i]; }
            const float inv = 1.f / ssum;
#pragma unroll
            for (int i = 0; i < 8; ++i) cij[i * 8 + oo] = e[i] * inv;
        }
        __syncthreads();
        float cf[8];
#pragma unroll
        for (int i = 0; i < 8; ++i) cf[i] = cij[i * 8 + o];
        float s[8];
#pragma unroll
        for (int j = 0; j < 8; ++j) {
            float acc = 0.f;
#pragma unroll
            for (int r = 0; r < 8; ++r) acc = fmaf(cf[r], C[r][j], acc);
            s[j] = acc;
        }
        float ssq = 0.f;
#pragma unroll
        for (int j = 0; j < 8; ++j) ssq = fmaf(s[j], s[j], ssq);
        ssq += __shfl_xor(ssq, 1);
        const float scale = ssq / ((1.f + ssq) * sqrtf(ssq));
        if (it == 2) {
#pragma unroll
            for (int j = 0; j < 8; ++j) vout[j] = s[j] * scale;
        } else {
            float ap[8];
#pragma unroll
            for (int r = 0; r < 8; ++r) {
                float acc = 0.f;
#pragma unroll
                for (int j = 0; j < 8; ++j) acc = fmaf(C[r][j], s[j] * scale, acc);
                ap[r] = acc;
            }
#pragma unroll
            for (int r = 0; r < 8; ++r) ap[r] += __shfl_xor(ap[r], 1);
            if ((tn & 1) == 0) {
#pragma unroll
                for (int r = 0; r < 8; ++r) aTmp2[tm * 64 + r * 8 + o] = ap[r];
            }
            __syncthreads();
            if (t < 64) {
                float acc = 0.f;
#pragma unroll
                for (int b = 0; b < BB; ++b) acc += aTmp2[b * 64 + t];
                bijs2[t] += acc * (1.f / 16.f);
            }
        }
    }
    if (direct_out) {
#pragma unroll
        for (int j = 0; j < 8; ++j)
            outbuf[(size_t)(tm * NOC + tn * 8 + j) * NPIX + p] = vout[j];
    } else {
        float4* dst = (float4*)(outbuf + (size_t)p * 2048 + tm * NOC + tn * 8);
        dst[0] = make_float4(vout[0], vout[1], vout[2], vout[3]);
        dst[1] = make_float4(vout[4], vout[5], vout[6], vout[7]);
    }
}

extern "C" void kernel_launch(void* const* d_in, const int* in_sizes, int n_in,
                              void* d_out, int out_size, void* d_ws, size_t ws_size,
                              hipStream_t stream)
{
    const float* x    = (const float*)d_in[0];
    const float* Wc   = (const float*)d_in[1];
    const float* bias = (const float*)d_in[2];
    float* out        = (float*)d_out;

    const size_t VT_BYTES = (size_t)NPIX * 2048 * sizeof(float);   // 34,611,200
    const size_t WB_OFF   = VT_BYTES;
    const size_t XB_OFF   = WB_OFF + 65536;
    const size_t TOTAL    = XB_OFF + (size_t)BI * CIN * WH * WH * 2;  // 101,785,600

    if (ws_size >= TOTAL) {
        float*   vtmp = (float*)d_ws;
        ushortT* Wbf  = (ushortT*)((char*)d_ws + WB_OFF);
        ushortT* xbf  = (ushortT*)((char*)d_ws + XB_OFF);

        cvt_x_kernel<<<8192, 256, 0, stream>>>((const float4*)x, (ushort4*)xbf,
                                               BI * CIN * WH * WH / 4);
        prep_w_kernel<<<128, 256, 0, stream>>>(Wc, Wbf);
        capsconv_mfma<<<529 * 8, 512, 0, stream>>>(xbf, Wbf, bias, vtmp, 0);
        dim3 g((NPIX + 31) / 32, 2048 / 32);
        transpose_kernel<<<g, 256, 0, stream>>>(vtmp, out);
    } else if (ws_size >= VT_BYTES) {
        float* vtmp = (float*)d_ws;
        capsconv_fp32<<<NPIX, 256, 0, stream>>>(x, Wc, bias, vtmp, 0);
        dim3 g((NPIX + 31) / 32, 2048 / 32);
        transpose_kernel<<<g, 256, 0, stream>>>(vtmp, out);
    } else {
        capsconv_fp32<<<NPIX, 256, 0, stream>>>(x, Wc, bias, out, 1);
    }
}